// Round 7
// baseline (1271.626 us; speedup 1.0000x reference)
//
#include <hip/hip_runtime.h>
#include <math.h>

#define Bsz  1024
#define Tlen 128
#define Hdim 512
#define NCLS 10
#define NDIG 3
#define G4   2048   // 4*H

typedef short s8v __attribute__((ext_vector_type(8)));   // 8 bf16 (4 VGPRs)
typedef float f4v __attribute__((ext_vector_type(4)));   // 16x16 mfma acc

// ---- workspace layout (bytes) ----
// W6 : 2 MB  bf16 B-frag chunks: uint4 idx = ((nt*8+w)*16 + ks)*64 + lane
//      lane l, elem j: n = nt*128 + w*16 + (l&15), k = ks*32 + (l>>4)*8 + j
//      (n = jp*4+g gate-interleaved, row = g*512+jp of Wh)
// gxd: 24 KB fp32 [d][jp*4+g]
// h0/h1: 1 MB bf16 each; per-chain 32 KB: uint4 idx = mt*2048 +
//      (ks*2+msub)*64 + q*16 + r  -> row msub*16+r, k = ks*32 + q*8 .. +7
// cnt: 4 KB (32 chain counters, stride 32 ints)
#define W6_OFF  0
#define GXD_OFF (2*1024*1024)
#define H0_OFF  (GXD_OFF + 32*1024)
#define H1_OFF  (H0_OFF + 1024*1024)
#define CNT_OFF (H1_OFF + 1024*1024)

static __device__ __forceinline__ unsigned short f2bf(float f) {
    unsigned int u = __float_as_uint(f);
    u = (u + 0x7FFFu + ((u >> 16) & 1u)) >> 16;   // RNE
    return (unsigned short)u;
}
static __device__ __forceinline__ float bf2f(unsigned short s) {
    return __uint_as_float(((unsigned int)s) << 16);
}
static __device__ __forceinline__ s8v u2s(uint4 v) {
    union { uint4 u; s8v s; } x; x.u = v; return x.s;
}

// ---- prep: W6 B-frag chunks (same as R6) ----
__global__ __launch_bounds__(256) void prep_w6(const float* __restrict__ Wh,
                                               unsigned short* __restrict__ W6) {
    int idx = blockIdx.x * 256 + threadIdx.x;   // 0..131071
    int l  = idx & 63;
    int c  = idx >> 6;            // (nt*8+w)*16 + ks
    int ks = c & 15;
    int wv = (c >> 4) & 7;
    int nt = c >> 7;              // 0..15
    int n  = nt * 128 + wv * 16 + (l & 15);
    int jp = n >> 2, g = n & 3;
    int row = g * Hdim + jp;
    int kb  = ks * 32 + (l >> 4) * 8;
    const float* src = &Wh[(size_t)row * Hdim + kb];
    unsigned int p0 = f2bf(src[0]) | ((unsigned int)f2bf(src[1]) << 16);
    unsigned int p1 = f2bf(src[2]) | ((unsigned int)f2bf(src[3]) << 16);
    unsigned int p2 = f2bf(src[4]) | ((unsigned int)f2bf(src[5]) << 16);
    unsigned int p3 = f2bf(src[6]) | ((unsigned int)f2bf(src[7]) << 16);
    ((uint4*)W6)[idx] = make_uint4(p0, p1, p2, p3);
}

__global__ __launch_bounds__(256) void prep_gxd(const float* __restrict__ emb,
                                                const float* __restrict__ Wx,
                                                const float* __restrict__ b,
                                                float* __restrict__ gxd) {
    int idx = blockIdx.x * 256 + threadIdx.x;
    if (idx >= NDIG * G4) return;
    int col = idx % G4;
    int d   = idx / G4;
    int jp  = col >> 2;
    int g   = col & 3;
    int row = g * Hdim + jp;
    gxd[idx] = emb[d * 2 + 0] * Wx[row * 2 + 0]
             + emb[d * 2 + 1] * Wx[row * 2 + 1]
             + b[row];
}

__global__ __launch_bounds__(256) void zero_state(float4* __restrict__ p, int n4) {
    int i = blockIdx.x * 256 + threadIdx.x;
    if (i < n4) p[i] = make_float4(0.f, 0.f, 0.f, 0.f);
}

// ---- persistent LSTM: 256 blocks (R5-proven shape), 2 chains per block ----
// blk: nt = blk&15 (128 gate-cols), pr = blk>>4 -> chains mt0=2pr, mt1=2pr+1.
// Each chain: 16 blocks, own counter, own h region. Phase0/phase1 alternate so
// each chain's L3 exchange latency hides under the other chain's compute.
__global__ __launch_bounds__(512, 2) void lstm_persist(
    const uint4* __restrict__ W6, const float* __restrict__ gxd,
    const int* __restrict__ x, uint4* __restrict__ h0, uint4* __restrict__ h1,
    int* __restrict__ cnt, const float* __restrict__ Wp,
    const float* __restrict__ bp, float* __restrict__ out)
{
    __shared__ uint4 h_s0[2048];       // 32 KB chain-0 A-frags
    __shared__ uint4 h_s1[2048];       // 32 KB chain-1 A-frags
    __shared__ float z_s[32 * 132];    // 16.9 KB z regroup (shared, per-phase)

    const int tid  = threadIdx.x;
    const int w    = tid >> 6;
    const int lane = tid & 63;
    const int nt   = blockIdx.x & 15;
    const int pr   = blockIdx.x >> 4;
    const int mt0  = pr * 2;
    const int mt1  = pr * 2 + 1;

    // B-resident W fragments: 16 chunks (n16 x k32) = 64 VGPRs
    s8v bres[16];
    {
        const uint4* wq = W6 + (size_t)((nt * 8 + w) * 16) * 64 + lane;
#pragma unroll
        for (int ks = 0; ks < 16; ks++) bres[ks] = u2s(wq[ks * 64]);
    }

    const int bl = tid & 31;          // row 0..31
    const int jq = tid >> 5;          // 0..15 -> jp-local pair jq*2, jq*2+1
    const int ldsa = (lane >> 4) * 16 + (lane & 15);
    // h-write dword offset inside a chain region
    const int hdw = ((nt * 2 + (bl >> 4)) * 64 + (jq >> 2) * 16 + (bl & 15)) * 4
                  + (jq & 3);
    float c00 = 0.f, c01 = 0.f;       // chain-0 c-state (jp jq*2, jq*2+1)
    float c10 = 0.f, c11 = 0.f;       // chain-1 c-state
    int* cnt0 = cnt + mt0 * 32;
    int* cnt1 = cnt + mt1 * 32;

#pragma unroll 1
    for (int t = 0; t < Tlen; t++) {
        const uint4* hr = (t & 1) ? h1 : h0;
        uint4*       hw = (t & 1) ? h0 : h1;

#pragma unroll
        for (int ph = 0; ph < 2; ph++) {
            const int   mt   = ph ? mt1 : mt0;
            int*        myc  = ph ? cnt1 : cnt0;
            uint4*      hs   = ph ? h_s1 : h_s0;
            float&      ca   = ph ? c10 : c00;
            float&      cb   = ph ? c11 : c01;

            // wait: all 16 chain blocks completed step t-1 (h(t) visible in L3)
            if (t > 0) {
                if (tid == 0) {
                    const int target = 16 * t;
                    while (__hip_atomic_load(myc, __ATOMIC_RELAXED,
                                             __HIP_MEMORY_SCOPE_AGENT) < target) {}
                }
                __syncthreads();
            }

            // stage A chunks via L3 (8B relaxed agent loads, coalesced)
            {
                const unsigned long long* hr8 =
                    (const unsigned long long*)(hr + mt * 2048);
                unsigned long long* hs8 = (unsigned long long*)hs;
#pragma unroll
                for (int u = 0; u < 8; u++) {
                    int i = tid + u * 512;
                    hs8[i] = __hip_atomic_load(hr8 + i, __ATOMIC_RELAXED,
                                               __HIP_MEMORY_SCOPE_AGENT);
                }
            }
            __syncthreads();

            // K loop: B from registers, A from LDS; wave = m32 x n16
            f4v acc0 = {0.f, 0.f, 0.f, 0.f};
            f4v acc1 = {0.f, 0.f, 0.f, 0.f};
#pragma unroll
            for (int ks = 0; ks < 16; ks++) {
                s8v a0 = u2s(hs[(ks * 2 + 0) * 64 + ldsa]);
                s8v a1 = u2s(hs[(ks * 2 + 1) * 64 + ldsa]);
                acc0 = __builtin_amdgcn_mfma_f32_16x16x32_bf16(a0, bres[ks], acc0, 0, 0, 0);
                acc1 = __builtin_amdgcn_mfma_f32_16x16x32_bf16(a1, bres[ks], acc1, 0, 0, 0);
            }

            // z scatter: C layout row=(l>>4)*4+reg, col=l&15
            {
                int colb = w * 16 + (lane & 15);
                int rb   = (lane >> 4) * 4;
#pragma unroll
                for (int r = 0; r < 4; r++) {
                    z_s[(rb + r) * 132 + colb]      = acc0[r];
                    z_s[(16 + rb + r) * 132 + colb] = acc1[r];
                }
            }
            __syncthreads();

            // epilogue: thread owns (row bl, jp-local jq*2 + {0,1})
            {
                int d = x[(mt * 32 + bl) * Tlen + t];
                const float* zr = &z_s[bl * 132 + jq * 8];
                const float* gx = &gxd[d * G4 + nt * 128 + jq * 8];
                float4 za = *(const float4*)zr;
                float4 zb = *(const float4*)(zr + 4);
                float4 ga = *(const float4*)gx;
                float4 gb = *(const float4*)(gx + 4);
                unsigned short hh[2];
                {
                    float zg = za.x + ga.x, zi = za.y + ga.y;
                    float zf = za.z + ga.z, zo = za.w + ga.w;
                    float gv = 1.f - 2.f / (__expf(2.f * zg) + 1.f);
                    float iv = 1.f / (1.f + __expf(-zi));
                    float fv = 1.f / (1.f + __expf(-zf));
                    float ov = 1.f / (1.f + __expf(-zo));
                    float cn = gv * iv + ca * fv;
                    ca = cn;
                    hh[0] = f2bf((1.f - 2.f / (__expf(2.f * cn) + 1.f)) * ov);
                }
                {
                    float zg = zb.x + gb.x, zi = zb.y + gb.y;
                    float zf = zb.z + gb.z, zo = zb.w + gb.w;
                    float gv = 1.f - 2.f / (__expf(2.f * zg) + 1.f);
                    float iv = 1.f / (1.f + __expf(-zi));
                    float fv = 1.f / (1.f + __expf(-zf));
                    float ov = 1.f / (1.f + __expf(-zo));
                    float cn = gv * iv + cb * fv;
                    cb = cn;
                    hh[1] = f2bf((1.f - 2.f / (__expf(2.f * cn) + 1.f)) * ov);
                }
                unsigned int hv = (unsigned int)hh[0] | ((unsigned int)hh[1] << 16);
                __hip_atomic_store((unsigned int*)(hw + mt * 2048) + hdw, hv,
                                   __ATOMIC_RELAXED, __HIP_MEMORY_SCOPE_AGENT);
            }

            // drain own stores to coherent point, then signal chain counter
            asm volatile("s_waitcnt vmcnt(0)" ::: "memory");
            __syncthreads();
            if (tid == 0)
                __hip_atomic_fetch_add(myc, 1, __ATOMIC_RELAXED,
                                       __HIP_MEMORY_SCOPE_AGENT);
        }
    }

    // ---- head (nt==0 blocks): both chains' 64 rows ----
    if (nt != 0) return;
    if (tid == 0) {
        while (__hip_atomic_load(cnt0, __ATOMIC_RELAXED,
                                 __HIP_MEMORY_SCOPE_AGENT) < 16 * Tlen) {}
        while (__hip_atomic_load(cnt1, __ATOMIC_RELAXED,
                                 __HIP_MEMORY_SCOPE_AGENT) < 16 * Tlen) {}
    }
    __syncthreads();

    float* wp_s = (float*)h_s0;   // 20 KB fits in 32 KB region
    for (int i = tid; i < Hdim * NCLS; i += 512) wp_s[i] = Wp[i];
    __syncthreads();

#pragma unroll 1
    for (int ch = 0; ch < 2; ch++) {
        const int mt = ch ? mt1 : mt0;
        const unsigned long long* hf8 =
            (const unsigned long long*)(h0 + mt * 2048);   // t=127 wrote h0
#pragma unroll
        for (int rr = 0; rr < 4; rr++) {
            int blr = w * 4 + rr;
            int b   = mt * 32 + blr;
            // lane covers k = lane*8..+7: ks=lane>>2, q=lane&3, msub=blr>>4
            int u4 = ((lane >> 2) * 2 + (blr >> 4)) * 64 + (lane & 3) * 16
                   + (blr & 15);
            unsigned long long lo = __hip_atomic_load(hf8 + u4 * 2,
                __ATOMIC_RELAXED, __HIP_MEMORY_SCOPE_AGENT);
            unsigned long long hi = __hip_atomic_load(hf8 + u4 * 2 + 1,
                __ATOMIC_RELAXED, __HIP_MEMORY_SCOPE_AGENT);
            union { unsigned long long q[2]; unsigned short s[8]; } hu;
            hu.q[0] = lo; hu.q[1] = hi;
            float a[NCLS];
#pragma unroll
            for (int c = 0; c < NCLS; c++) a[c] = 0.f;
#pragma unroll
            for (int j = 0; j < 8; j++) {
                int k = lane * 8 + j;
                float hvv = bf2f(hu.s[j]);
#pragma unroll
                for (int c = 0; c < NCLS; c++) a[c] += hvv * wp_s[k * NCLS + c];
            }
#pragma unroll
            for (int off = 32; off > 0; off >>= 1) {
#pragma unroll
                for (int c = 0; c < NCLS; c++) a[c] += __shfl_down(a[c], off);
            }
            if (lane == 0) {
                float p[NCLS], m = -1e30f;
#pragma unroll
                for (int c = 0; c < NCLS; c++) { p[c] = a[c] + bp[c]; m = fmaxf(m, p[c]); }
                float s = 0.f;
#pragma unroll
                for (int c = 0; c < NCLS; c++) s += __expf(p[c] - m);
                float lse = m + logf(s);
#pragma unroll
                for (int c = 0; c < NCLS; c++) out[b * NCLS + c] = p[c] - lse;
            }
        }
    }
}

extern "C" void kernel_launch(void* const* d_in, const int* in_sizes, int n_in,
                              void* d_out, int out_size, void* d_ws, size_t ws_size,
                              hipStream_t stream) {
    const int*   x   = (const int*)d_in[0];
    const float* emb = (const float*)d_in[1];
    const float* Wx  = (const float*)d_in[2];
    const float* Wh  = (const float*)d_in[3];
    const float* b   = (const float*)d_in[4];
    const float* Wp  = (const float*)d_in[5];
    const float* bp  = (const float*)d_in[6];
    float* out = (float*)d_out;
    char*  ws  = (char*)d_ws;

    unsigned short* W6  = (unsigned short*)(ws + W6_OFF);
    float*          gxd = (float*)(ws + GXD_OFF);
    uint4*          h0  = (uint4*)(ws + H0_OFF);
    uint4*          h1  = (uint4*)(ws + H1_OFF);
    int*            cnt = (int*)(ws + CNT_OFF);

    prep_w6<<<512, 256, 0, stream>>>(Wh, W6);
    prep_gxd<<<(NDIG * G4 + 255) / 256, 256, 0, stream>>>(emb, Wx, b, gxd);
    // zero h0 + h1 + counters (2 MB + 4 KB contiguous)
    {
        int n4 = (2 * 1024 * 1024 + 4096) / 16;
        zero_state<<<(n4 + 255) / 256, 256, 0, stream>>>((float4*)h0, n4);
    }

    void* args[] = { (void*)&W6, (void*)&gxd, (void*)&x, (void*)&h0, (void*)&h1,
                     (void*)&cnt, (void*)&Wp, (void*)&bp, (void*)&out };
    hipLaunchCooperativeKernel((void*)lstm_persist, dim3(256), dim3(512),
                               args, 0, stream);
}

// Round 8
// 1199.275 us; speedup vs baseline: 1.0603x; 1.0603x over previous
//
#include <hip/hip_runtime.h>
#include <math.h>

#define Bsz  1024
#define Tlen 128
#define Hdim 512
#define NCLS 10
#define NDIG 3
#define G4   2048   // 4*H

typedef short s8v __attribute__((ext_vector_type(8)));    // 8 bf16 (4 VGPRs)
typedef float f16v __attribute__((ext_vector_type(16)));  // 32x32 mfma acc

// ---- workspace layout (bytes) ----
// W6 : 2 MB  bf16 B-frag chunks: uint4 idx = (wn*32+ks)*64 + lane, wn=0..63
//      lane l elem j: n = wn*32+(l&31) -> jp=n>>2,g=n&3, row=g*512+jp,
//      k = ks*16 + (l>>5)*8 + j
// gxd: 24 KB fp32 [d][jp*4+g]
// h0/h1: 1 MB bf16 each; per-chain 32 KB: uint4 idx = mt*2048 + ks*64 + l
//      elem j = h[row = l&31][k = ks*16 + (l>>5)*8 + j]   (32 rows x 512 k)
// cnt: 4 KB (32 chain counters, stride 32 ints)
#define W6_OFF  0
#define GXD_OFF (2*1024*1024)
#define H0_OFF  (GXD_OFF + 32*1024)
#define H1_OFF  (H0_OFF + 1024*1024)
#define CNT_OFF (H1_OFF + 1024*1024)

static __device__ __forceinline__ unsigned short f2bf(float f) {
    unsigned int u = __float_as_uint(f);
    u = (u + 0x7FFFu + ((u >> 16) & 1u)) >> 16;   // RNE
    return (unsigned short)u;
}
static __device__ __forceinline__ float bf2f(unsigned short s) {
    return __uint_as_float(((unsigned int)s) << 16);
}
static __device__ __forceinline__ s8v u2s(uint4 v) {
    union { uint4 u; s8v s; } x; x.u = v; return x.s;
}

// ---- prep: W6 B-frag chunks (R5 layout, 64 n-tiles of 32 cols) ----
__global__ __launch_bounds__(256) void prep_w6(const float* __restrict__ Wh,
                                               unsigned short* __restrict__ W6) {
    int idx = blockIdx.x * 256 + threadIdx.x;   // 0..131071
    int l  = idx & 63;
    int c  = idx >> 6;          // wn*32 + ks
    int ks = c & 31, wn = c >> 5;
    int n  = wn * 32 + (l & 31);
    int jp = n >> 2, g = n & 3;
    int row = g * Hdim + jp;
    int kb  = ks * 16 + (l >> 5) * 8;
    const float* src = &Wh[(size_t)row * Hdim + kb];
    unsigned int p0 = f2bf(src[0]) | ((unsigned int)f2bf(src[1]) << 16);
    unsigned int p1 = f2bf(src[2]) | ((unsigned int)f2bf(src[3]) << 16);
    unsigned int p2 = f2bf(src[4]) | ((unsigned int)f2bf(src[5]) << 16);
    unsigned int p3 = f2bf(src[6]) | ((unsigned int)f2bf(src[7]) << 16);
    ((uint4*)W6)[idx] = make_uint4(p0, p1, p2, p3);
}

__global__ __launch_bounds__(256) void prep_gxd(const float* __restrict__ emb,
                                                const float* __restrict__ Wx,
                                                const float* __restrict__ b,
                                                float* __restrict__ gxd) {
    int idx = blockIdx.x * 256 + threadIdx.x;
    if (idx >= NDIG * G4) return;
    int col = idx % G4;
    int d   = idx / G4;
    int jp  = col >> 2;
    int g   = col & 3;
    int row = g * Hdim + jp;
    gxd[idx] = emb[d * 2 + 0] * Wx[row * 2 + 0]
             + emb[d * 2 + 1] * Wx[row * 2 + 1]
             + b[row];
}

__global__ __launch_bounds__(256) void zero_state(float4* __restrict__ p, int n4) {
    int i = blockIdx.x * 256 + threadIdx.x;
    if (i < n4) p[i] = make_float4(0.f, 0.f, 0.f, 0.f);
}

// ---- persistent LSTM: 256 blocks x 512 thr; 2 independent half-blocks ----
// Half-block (4 waves, 256 thr) = one member of one chain. 32 chains x 16
// half-blocks; chain mt = (blk>>4)*2 + half, nt = blk&15 (128 gate-cols).
// Halves sync via LDS split barriers (NOT __syncthreads), so one half's
// chain-exchange latency is hidden under the other half's compute.
__global__ __launch_bounds__(512, 2) void lstm_persist(
    const uint4* __restrict__ W6, const float* __restrict__ gxd,
    const int* __restrict__ x, uint4* __restrict__ h0, uint4* __restrict__ h1,
    int* __restrict__ cnt, const float* __restrict__ Wp,
    const float* __restrict__ bp, float* __restrict__ out)
{
    __shared__ uint4 h_sA[2048];       // 32 KB  half-A A-frags
    __shared__ uint4 h_sB[2048];       // 32 KB  half-B A-frags
    __shared__ float z_sA[32 * 132];   // 16.9 KB half-A z regroup
    __shared__ float z_sB[32 * 132];   // 16.9 KB half-B z regroup
    __shared__ int   hbc[2];           // split-barrier counters

    const int tid  = threadIdx.x;
    const int half = tid >> 8;         // 0/1
    const int thrA = tid & 255;        // index within half-block
    const int wl   = (tid >> 6) & 3;   // wave within half-block
    const int lane = tid & 63;
    const int nt   = blockIdx.x & 15;
    const int mt   = (blockIdx.x >> 4) * 2 + half;

    if (tid < 2) hbc[tid] = 0;
    __syncthreads();                   // only block-wide sync (init)

    uint4* hs = half ? h_sB : h_sA;
    float* zs = half ? z_sB : z_sA;
    int*  mycnt = cnt + mt * 32;
    int   bcnt = 0;

    // split-barrier: 4 waves of this half
#define HB_BAR_FAST() do { bcnt += 4;                                         \
    if (lane == 0) atomicAdd(&hbc[half], 1);                                  \
    while (__hip_atomic_load(&hbc[half], __ATOMIC_RELAXED,                    \
                             __HIP_MEMORY_SCOPE_WORKGROUP) < bcnt) {} } while (0)
#define HB_BAR_SLEEP() do { bcnt += 4;                                        \
    if (lane == 0) atomicAdd(&hbc[half], 1);                                  \
    while (__hip_atomic_load(&hbc[half], __ATOMIC_RELAXED,                    \
                             __HIP_MEMORY_SCOPE_WORKGROUP) < bcnt)            \
        __builtin_amdgcn_s_sleep(1); } while (0)

    // B-resident W fragments: wave n-tile wn = nt*4 + wl (32 cols), 128 VGPRs
    s8v bres[32];
    {
        const uint4* wq = W6 + (size_t)((nt * 4 + wl) * 32) * 64 + lane;
#pragma unroll
        for (int ks = 0; ks < 32; ks++) bres[ks] = u2s(wq[ks * 64]);
    }

    const int bl = thrA & 31;          // row 0..31
    const int jg = thrA >> 5;          // 0..7 -> jp-local jg*4 .. +3
    float c0 = 0.f, c1 = 0.f, c2 = 0.f, c3 = 0.f;
    // h-write (ushort units) for (bl, jp0 = nt*32 + jg*4)
    const int hus = ((nt * 2 + (jg >> 2)) * 64 + ((jg >> 1) & 1) * 32 + bl) * 8
                  + (jg & 1) * 4;
    const int xoff = (mt * 32 + bl) * Tlen;

#pragma unroll 1
    for (int t = 0; t < Tlen; t++) {
        const uint4* hr = (t & 1) ? h1 : h0;
        uint4*       hw = (t & 1) ? h0 : h1;

        // stage this chain's 32 KB h tile via L3 (relaxed agent 8B loads)
        {
            const unsigned long long* hr8 =
                (const unsigned long long*)(hr + mt * 2048);
            unsigned long long* hs8 = (unsigned long long*)hs;
#pragma unroll
            for (int u = 0; u < 16; u++) {
                int i = thrA + u * 256;
                hs8[i] = __hip_atomic_load(hr8 + i, __ATOMIC_RELAXED,
                                           __HIP_MEMORY_SCOPE_AGENT);
            }
        }
        asm volatile("s_waitcnt lgkmcnt(0) vmcnt(0)" ::: "memory");
        HB_BAR_FAST();                 // B1: stage complete

        // K loop: B from registers, A from LDS; wave = m32 x n32
        f16v acc = {0,0,0,0,0,0,0,0,0,0,0,0,0,0,0,0};
#pragma unroll
        for (int ks = 0; ks < 32; ks++) {
            s8v a = u2s(hs[ks * 64 + lane]);
            acc = __builtin_amdgcn_mfma_f32_32x32x16_bf16(a, bres[ks], acc, 0, 0, 0);
        }

        // z scatter (C layout: col=lane&31, row=(r&3)+8*(r>>2)+4*(lane>>5))
        {
            int colb = wl * 32 + (lane & 31);
            int rb   = 4 * (lane >> 5);
#pragma unroll
            for (int r = 0; r < 16; r++) {
                int row = (r & 3) + 8 * (r >> 2) + rb;
                zs[row * 132 + colb] = acc[r];
            }
        }
        asm volatile("s_waitcnt lgkmcnt(0)" ::: "memory");
        HB_BAR_FAST();                 // B2: h_s reads + z writes done

        // epilogue: thread owns (row bl, jp-local jg*4 .. +3)
        {
            int d = x[xoff + t];
            const float* zr = &zs[bl * 132 + jg * 16];
            const float* gx = &gxd[d * G4 + nt * 128 + jg * 16];
            unsigned short hh[4];
            float cc[4] = {c0, c1, c2, c3};
#pragma unroll
            for (int i = 0; i < 4; i++) {
                float4 z4 = *(const float4*)(zr + i * 4);
                float4 g4 = *(const float4*)(gx + i * 4);
                float zg = z4.x + g4.x, zi = z4.y + g4.y;
                float zf = z4.z + g4.z, zo = z4.w + g4.w;
                float gv = 1.f - 2.f / (__expf(2.f * zg) + 1.f);
                float iv = 1.f / (1.f + __expf(-zi));
                float fv = 1.f / (1.f + __expf(-zf));
                float ov = 1.f / (1.f + __expf(-zo));
                float cn = gv * iv + cc[i] * fv;
                cc[i] = cn;
                hh[i] = f2bf((1.f - 2.f / (__expf(2.f * cn) + 1.f)) * ov);
            }
            c0 = cc[0]; c1 = cc[1]; c2 = cc[2]; c3 = cc[3];
            unsigned long long hv8 =
                  (unsigned long long)hh[0]
                | ((unsigned long long)hh[1] << 16)
                | ((unsigned long long)hh[2] << 32)
                | ((unsigned long long)hh[3] << 48);
            __hip_atomic_store(
                (unsigned long long*)((unsigned short*)(hw + mt * 2048) + hus),
                hv8, __ATOMIC_RELAXED, __HIP_MEMORY_SCOPE_AGENT);
        }
        asm volatile("s_waitcnt lgkmcnt(0) vmcnt(0)" ::: "memory");
        HB_BAR_FAST();                 // B3: h stores drained, z reads done

        // chain signal + wait (leader), other half's waves compute meanwhile
        if (thrA == 0)
            __hip_atomic_fetch_add(mycnt, 1, __ATOMIC_RELAXED,
                                   __HIP_MEMORY_SCOPE_AGENT);
        if (thrA == 0) {
            const int target = 16 * (t + 1);
            while (__hip_atomic_load(mycnt, __ATOMIC_RELAXED,
                                     __HIP_MEMORY_SCOPE_AGENT) < target)
                __builtin_amdgcn_s_sleep(1);
        }
        HB_BAR_SLEEP();                // B4: chain step complete
    }

    // ---- head (nt==0 blocks): each half does its chain's 32 rows ----
    if (nt != 0) return;
    float* wp_s = (float*)hs;          // 20 KB into this half's 32 KB region
    for (int i = thrA; i < Hdim * NCLS; i += 256) wp_s[i] = Wp[i];
    asm volatile("s_waitcnt lgkmcnt(0)" ::: "memory");
    HB_BAR_FAST();

    const unsigned long long* hf8 =
        (const unsigned long long*)(h0 + mt * 2048);   // t=127 wrote h0
#pragma unroll 1
    for (int rr = 0; rr < 8; rr++) {
        int row = wl * 8 + rr;
        int b   = mt * 32 + row;
        // lane covers k = lane*8..+7: u4 = (lane>>1)*64 + (lane&1)*32 + row
        int u4 = (lane >> 1) * 64 + (lane & 1) * 32 + row;
        unsigned long long lo = __hip_atomic_load(hf8 + u4 * 2,
            __ATOMIC_RELAXED, __HIP_MEMORY_SCOPE_AGENT);
        unsigned long long hi = __hip_atomic_load(hf8 + u4 * 2 + 1,
            __ATOMIC_RELAXED, __HIP_MEMORY_SCOPE_AGENT);
        union { unsigned long long q[2]; unsigned short s[8]; } hu;
        hu.q[0] = lo; hu.q[1] = hi;
        float a[NCLS];
#pragma unroll
        for (int c = 0; c < NCLS; c++) a[c] = 0.f;
#pragma unroll
        for (int j = 0; j < 8; j++) {
            int k = lane * 8 + j;
            float hvv = bf2f(hu.s[j]);
#pragma unroll
            for (int c = 0; c < NCLS; c++) a[c] += hvv * wp_s[k * NCLS + c];
        }
#pragma unroll
        for (int off = 32; off > 0; off >>= 1) {
#pragma unroll
            for (int c = 0; c < NCLS; c++) a[c] += __shfl_down(a[c], off);
        }
        if (lane == 0) {
            float p[NCLS], m = -1e30f;
#pragma unroll
            for (int c = 0; c < NCLS; c++) { p[c] = a[c] + bp[c]; m = fmaxf(m, p[c]); }
            float s = 0.f;
#pragma unroll
            for (int c = 0; c < NCLS; c++) s += __expf(p[c] - m);
            float lse = m + logf(s);
#pragma unroll
            for (int c = 0; c < NCLS; c++) out[b * NCLS + c] = p[c] - lse;
        }
    }
#undef HB_BAR_FAST
#undef HB_BAR_SLEEP
}

extern "C" void kernel_launch(void* const* d_in, const int* in_sizes, int n_in,
                              void* d_out, int out_size, void* d_ws, size_t ws_size,
                              hipStream_t stream) {
    const int*   x   = (const int*)d_in[0];
    const float* emb = (const float*)d_in[1];
    const float* Wx  = (const float*)d_in[2];
    const float* Wh  = (const float*)d_in[3];
    const float* b   = (const float*)d_in[4];
    const float* Wp  = (const float*)d_in[5];
    const float* bp  = (const float*)d_in[6];
    float* out = (float*)d_out;
    char*  ws  = (char*)d_ws;

    unsigned short* W6  = (unsigned short*)(ws + W6_OFF);
    float*          gxd = (float*)(ws + GXD_OFF);
    uint4*          h0  = (uint4*)(ws + H0_OFF);
    uint4*          h1  = (uint4*)(ws + H1_OFF);
    int*            cnt = (int*)(ws + CNT_OFF);

    prep_w6<<<512, 256, 0, stream>>>(Wh, W6);
    prep_gxd<<<(NDIG * G4 + 255) / 256, 256, 0, stream>>>(emb, Wx, b, gxd);
    // zero h0 + h1 + counters (2 MB + 4 KB contiguous)
    {
        int n4 = (2 * 1024 * 1024 + 4096) / 16;
        zero_state<<<(n4 + 255) / 256, 256, 0, stream>>>((float4*)h0, n4);
    }

    void* args[] = { (void*)&W6, (void*)&gxd, (void*)&x, (void*)&h0, (void*)&h1,
                     (void*)&cnt, (void*)&Wp, (void*)&bp, (void*)&out };
    hipLaunchCooperativeKernel((void*)lstm_persist, dim3(256), dim3(512),
                               args, 0, stream);
}